// Round 3
// baseline (18101.154 us; speedup 1.0000x reference)
//
#include <hip/hip_runtime.h>
#include <math.h>

typedef __attribute__((ext_vector_type(8))) short bf16x8;  // 8 bf16 = 4 VGPR
typedef __attribute__((ext_vector_type(4))) short bf16x4;  // 8 B
typedef __attribute__((ext_vector_type(4))) float f32x4;   // C/D frag

#define SSCL (0.08838834764831845f * 1.4426950408889634f)  // 1/sqrt(128) * log2(e)

__device__ __forceinline__ short f2bf(float f) {
    union { float f; unsigned u; } x; x.f = f;
    unsigned r = x.u + 0x7fffu + ((x.u >> 16) & 1u);
    return (short)(r >> 16);
}
__device__ __forceinline__ float bf2f(short s) {
    union { unsigned u; float f; } x;
    x.u = ((unsigned)(unsigned short)s) << 16;
    return x.f;
}

typedef const __attribute__((address_space(1))) unsigned int* gas_ptr;
typedef __attribute__((address_space(3))) unsigned int* las_ptr;
__device__ __forceinline__ void async_copy16(const void* g, void* l) {
    __builtin_amdgcn_global_load_lds((gas_ptr)g, (las_ptr)l, 16, 0, 0);
}

// ---------------------------------------------------------------------------
// fp32 -> bf16 conversion pre-pass (vectorized, grid-stride). n4 = nelem/4.
// ---------------------------------------------------------------------------
__global__ __launch_bounds__(256)
void cvt_kernel(const float* __restrict__ src, short* __restrict__ dst, int n4) {
    int i = blockIdx.x * 256 + threadIdx.x;
    const int stride = gridDim.x * 256;
    for (; i < n4; i += stride) {
        float4 v = ((const float4*)src)[i];
        bf16x4 o;
        o[0] = f2bf(v.x); o[1] = f2bf(v.y); o[2] = f2bf(v.z); o[3] = f2bf(v.w);
        ((bf16x4*)dst)[i] = o;
    }
}

// ---------------------------------------------------------------------------
// NT GEMM (m97 pattern): D[m,n] = sum_k A[m,k]*B[n,k], bf16 in, fp32 acc.
// QKV=1: blockIdx.x in [0,48), sel=bx>>4: sel0 -> D16 (bf16, Q scratch),
//        sel1/2 -> Dk/Dv fp32 with kv-append row map m + ((m>>11)+1)*2048.
// QKV=0: blockIdx.x in [0,16), D = Df fp32 plain [4096,2048].
// ---------------------------------------------------------------------------
template<int QKV>
__global__ __launch_bounds__(256)
void gemm_kernel(const short* __restrict__ A,
                 const short* __restrict__ B0, const short* __restrict__ B1,
                 const short* __restrict__ B2,
                 short* __restrict__ D16, float* __restrict__ Dk,
                 float* __restrict__ Dv, float* __restrict__ Df) {
    __shared__ short As[128 * 64];
    __shared__ short Bs[128 * 64];
    const int tid = threadIdx.x, w = tid >> 6, ln = tid & 63;
    const int col = ln & 15, quad = ln >> 4;
    const int sel = QKV ? (blockIdx.x >> 4) : 0;
    const int tn = (blockIdx.x & 15) * 128;
    const int tm = blockIdx.y * 128;
    const short* B = (sel == 0) ? B0 : ((sel == 1) ? B1 : B2);

    const int wm = (w >> 1) * 64, wn = (w & 1) * 64;
    const int srow = ln >> 3, scol = (ln & 7) * 8;

    f32x4 acc[4][4];
    for (int i = 0; i < 4; ++i)
        for (int j = 0; j < 4; ++j)
            for (int e = 0; e < 4; ++e) acc[i][j][e] = 0.f;

    for (int k0 = 0; k0 < 2048; k0 += 64) {
        #pragma unroll
        for (int i = 0; i < 4; ++i) {
            int chunk = i * 4 + w;
            int row = chunk * 8 + srow;
            async_copy16(&A[(tm + row) * 2048 + k0 + scol], &As[chunk * 512]);
            async_copy16(&B[(tn + row) * 2048 + k0 + scol], &Bs[chunk * 512]);
        }
        asm volatile("s_waitcnt vmcnt(0)" ::: "memory");
        __syncthreads();
        #pragma unroll
        for (int kk = 0; kk < 2; ++kk) {
            bf16x8 af[4], bfr[4];
            #pragma unroll
            for (int i = 0; i < 4; ++i)
                af[i] = *(const bf16x8*)&As[(wm + i * 16 + col) * 64 + kk * 32 + quad * 8];
            #pragma unroll
            for (int j = 0; j < 4; ++j)
                bfr[j] = *(const bf16x8*)&Bs[(wn + j * 16 + col) * 64 + kk * 32 + quad * 8];
            #pragma unroll
            for (int i = 0; i < 4; ++i)
                #pragma unroll
                for (int j = 0; j < 4; ++j)
                    acc[i][j] = __builtin_amdgcn_mfma_f32_16x16x32_bf16(af[i], bfr[j], acc[i][j], 0, 0, 0);
        }
        __syncthreads();
    }
    // epilogue: C/D layout col = lane&15, row = quad*4 + reg
    for (int i = 0; i < 4; ++i)
        for (int j = 0; j < 4; ++j)
            for (int r = 0; r < 4; ++r) {
                int m = tm + wm + i * 16 + quad * 4 + r;
                int n = tn + wn + j * 16 + col;
                float v = acc[i][j][r];
                if (QKV) {
                    if (sel == 0) {
                        D16[m * 2048 + n] = f2bf(v);
                    } else {
                        int orow = m + ((m >> 11) + 1) * 2048;
                        float* D = (sel == 1) ? Dk : Dv;
                        D[orow * 2048 + n] = v;
                    }
                } else {
                    Df[m * 2048 + n] = v;
                }
            }
}

// ---------------------------------------------------------------------------
// Simple flash attention (correctness-first). grid (512,16,2), block 256 =
// 4 waves; wave w owns q-row q0+w; lane ln owns dims ln and ln+64.
// K/V fp32 in global, converted to bf16 while staged into LDS (132 pad).
// Causal handled by per-wave visible-key count.
// ---------------------------------------------------------------------------
__global__ __launch_bounds__(256)
void attn_simple(const short* __restrict__ Q, const float* __restrict__ Kall,
                 const float* __restrict__ Vall, short* __restrict__ Ot) {
    __shared__ short Ks[64 * 132];
    __shared__ short Vs[64 * 132];
    const int tid = threadIdx.x, w = tid >> 6, ln = tid & 63;
    const int q0 = blockIdx.x * 4;
    const int h = blockIdx.y, b = blockIdx.z;
    const int q = q0 + w;
    const int row = b * 2048 + q;
    const float* Kb = Kall + (size_t)(b * 4096 * 16 + h) * 128;
    const float* Vb = Vall + (size_t)(b * 4096 * 16 + h) * 128;

    const float q_lo = bf2f(Q[row * 2048 + h * 128 + ln]);
    const float q_hi = bf2f(Q[row * 2048 + h * 128 + 64 + ln]);

    float m = -1e30f, l = 0.f, o_lo = 0.f, o_hi = 0.f;
    const int nvis = 2048 + q + 1;                    // visible keys for this wave
    const int ntiles = (2048 + q0 + 4 + 63) >> 6;     // block-uniform trip count

    for (int kt = 0; kt < ntiles; ++kt) {
        const int kp0 = kt * 64;
        __syncthreads();   // protect previous tile's reads before overwrite
        #pragma unroll
        for (int i = 0; i < 8; ++i) {
            int idx = i * 256 + tid;
            int r = idx >> 5, c = (idx & 31) * 4;
            float4 kv = *(const float4*)&Kb[(size_t)(kp0 + r) * 2048 + c];
            float4 vv = *(const float4*)&Vb[(size_t)(kp0 + r) * 2048 + c];
            bf16x4 ko, vo;
            ko[0] = f2bf(kv.x); ko[1] = f2bf(kv.y); ko[2] = f2bf(kv.z); ko[3] = f2bf(kv.w);
            vo[0] = f2bf(vv.x); vo[1] = f2bf(vv.y); vo[2] = f2bf(vv.z); vo[3] = f2bf(vv.w);
            *(bf16x4*)&Ks[r * 132 + c] = ko;
            *(bf16x4*)&Vs[r * 132 + c] = vo;
        }
        __syncthreads();
        int nk = nvis - kp0; if (nk > 64) nk = 64;
        for (int kk = 0; kk < nk; ++kk) {
            float s = q_lo * bf2f(Ks[kk * 132 + ln]) + q_hi * bf2f(Ks[kk * 132 + 64 + ln]);
            s += __shfl_xor(s, 1);
            s += __shfl_xor(s, 2);
            s += __shfl_xor(s, 4);
            s += __shfl_xor(s, 8);
            s += __shfl_xor(s, 16);
            s += __shfl_xor(s, 32);
            s *= SSCL;
            float mn = fmaxf(m, s);
            float al = exp2f(m - mn);
            float p = exp2f(s - mn);
            m = mn;
            l = l * al + p;
            o_lo = o_lo * al + p * bf2f(Vs[kk * 132 + ln]);
            o_hi = o_hi * al + p * bf2f(Vs[kk * 132 + 64 + ln]);
        }
    }
    const float inv = 1.f / l;
    Ot[row * 2048 + h * 128 + ln]      = f2bf(o_lo * inv);
    Ot[row * 2048 + h * 128 + 64 + ln] = f2bf(o_hi * inv);
}

// ---------------------------------------------------------------------------
extern "C" void kernel_launch(void* const* d_in, const int* in_sizes, int n_in,
                              void* d_out, int out_size, void* d_ws, size_t ws_size,
                              hipStream_t stream) {
    const float* x  = (const float*)d_in[0];
    const float* pk = (const float*)d_in[1];
    const float* pv = (const float*)d_in[2];
    // d_in[3] = mask (unused: causal structure reproduced analytically)
    const float* wq = (const float*)d_in[4];
    const float* wk = (const float*)d_in[5];
    const float* wv = (const float*)d_in[6];
    const float* wo = (const float*)d_in[7];

    float* out  = (float*)d_out;                 // [2][2048][2048]
    float* kall = out + 8388608;                 // [2][4096][16][128]
    float* vall = out + 25165824;                // [2][4096][16][128]

    short* ws16 = (short*)d_ws;
    short* xb  = ws16;               // [4096][2048] bf16 (reused as ot after gemm1)
    short* wqb = ws16 + 8388608;     // [2048][2048] bf16
    short* wkb = ws16 + 12582912;
    short* wvb = ws16 + 16777216;
    short* wob = ws16 + 20971520;
    short* qbf = ws16 + 25165824;    // [4096][2048] bf16
    short* ot  = xb;                 // alias: xb dead after gemm1

    // history -> kv cache, bit-exact fp32 (per batch: 4,194,304 floats = 16 MiB)
    hipMemcpyAsync(kall,           pk,           16777216u, hipMemcpyDeviceToDevice, stream);
    hipMemcpyAsync(kall + 8388608, pk + 4194304, 16777216u, hipMemcpyDeviceToDevice, stream);
    hipMemcpyAsync(vall,           pv,           16777216u, hipMemcpyDeviceToDevice, stream);
    hipMemcpyAsync(vall + 8388608, pv + 4194304, 16777216u, hipMemcpyDeviceToDevice, stream);

    // fp32 -> bf16 pre-pass for x and weights
    cvt_kernel<<<1024, 256, 0, stream>>>(x,  xb,  2097152);
    cvt_kernel<<<512,  256, 0, stream>>>(wq, wqb, 1048576);
    cvt_kernel<<<512,  256, 0, stream>>>(wk, wkb, 1048576);
    cvt_kernel<<<512,  256, 0, stream>>>(wv, wvb, 1048576);
    cvt_kernel<<<512,  256, 0, stream>>>(wo, wob, 1048576);

    // fused QKV projection: Q -> qbf (bf16), K/V chunk -> kall/vall (fp32)
    gemm_kernel<1><<<dim3(48, 32), 256, 0, stream>>>(xb, wqb, wkb, wvb,
                                                     qbf, kall, vall, nullptr);
    // attention (simple, correctness-first)
    attn_simple<<<dim3(512, 16, 2), 256, 0, stream>>>(qbf, kall, vall, ot);
    // output projection -> out (fp32)
    gemm_kernel<0><<<dim3(16, 32), 256, 0, stream>>>(ot, wob, wob, wob,
                                                     nullptr, nullptr, nullptr, out);
}